// Round 6
// baseline (428.110 us; speedup 1.0000x reference)
//
#include <hip/hip_runtime.h>

// ---------------------------------------------------------------------------
// TransformerBlock (B=4,S=2048,E=1024,H=16,Dh=64), fp32 (or bf16) in, fp32
// (or bf16) out — dtype auto-detected; all compute in bf16 MFMA w/ fp32 accum.
// Pipeline: cvt-to-bf16 -> fused QKV gemm -> flash attn -> Wo gemm (+x) ->
//           norm1 -> FFN1 (relu) -> FFN2 (+h) -> norm2 -> out
// R12-attn: both Q-halves fused, K/V LDS reads halved (kept).
// R13: gemm8ph (QKV/FFN1): faithful m201 8-phase schedule. 256x256, BK=64,
//      512 thr (8 waves 2Mx4N, per-wave 128x64), 2x64KB LDS buffers, 2
//      K-tiles per iter.  Per phase: {ds_reads quadrant ; stage 1 half-tile
//      (2 gl2lds) ; s_barrier ; lgkmcnt(0)+sched_barrier ; setprio1 ;
//      16 MFMA ; setprio0 ; s_barrier}.  vmcnt(4) ONLY at ph3/ph7-end
//      (before the closing barrier; cross-wave safe), vmcnt(0) only in the
//      last iter.  Half-tile stage ledger:
//        ph0:T1.A0 ph1:T1.A1 ph2:T2.B0 ph3:T2.B1
//        ph4:T2.A0 ph5:T2.A1 ph6:T3.B0 ph7:T3.B1   (T2=2i+2, T3=2i+3)
//      (B halves of a buffer free after its ph1; A halves after its ph2.)
//      Wo/FFN2 keep R4 gemm2<EPI,128> (3 bufs, distance-2, vmcnt(6)).
// ---------------------------------------------------------------------------

typedef __attribute__((ext_vector_type(8))) short s16x8;
typedef __attribute__((ext_vector_type(4))) short s16x4;
typedef __attribute__((ext_vector_type(4))) unsigned short u16x4;
typedef __attribute__((ext_vector_type(4))) float f32x4;

__device__ __forceinline__ float bf2f(unsigned short u) {
  unsigned int v = ((unsigned int)u) << 16;
  return __builtin_bit_cast(float, v);
}
__device__ __forceinline__ unsigned short f2bf(float f) {
  unsigned int u = __builtin_bit_cast(unsigned int, f);
  u += 0x7fffu + ((u >> 16) & 1u);   // RNE
  return (unsigned short)(u >> 16);
}
__device__ __forceinline__ unsigned int pkbf_trunc(float f0, float f1) {
  return __builtin_amdgcn_perm(__builtin_bit_cast(unsigned int, f1),
                               __builtin_bit_cast(unsigned int, f0), 0x07060302u);
}
__device__ __forceinline__ f32x4 mfma16(s16x8 a, s16x8 b, f32x4 c) {
  return __builtin_amdgcn_mfma_f32_16x16x32_bf16(a, b, c, 0, 0, 0);
}
__device__ __forceinline__ void gl2lds16(const unsigned short* g, unsigned short* l) {
  __builtin_amdgcn_global_load_lds(
      (const __attribute__((address_space(1))) unsigned int*)(g),
      (__attribute__((address_space(3))) unsigned int*)(l), 16, 0, 0);
}

// ---------------------------------------------------------------------------
__global__ void detect_dtype(const unsigned int* __restrict__ x, int* __restrict__ flag) {
  const int tid = threadIdx.x;
  int cnt = 0;
  for (int i = tid; i < 2048; i += 256) {
    const unsigned e = (x[i] >> 7) & 0xFF;
    cnt += (e >= 100 && e <= 150) ? 1 : 0;
  }
#pragma unroll
  for (int off = 32; off >= 1; off >>= 1) cnt += __shfl_xor(cnt, off);
  __shared__ int red[4];
  if ((tid & 63) == 0) red[tid >> 6] = cnt;
  __syncthreads();
  if (tid == 0) *flag = ((red[0] + red[1] + red[2] + red[3]) > 1536) ? 1 : 0;
}

// ---------------------------------------------------------------------------
struct CvtArgs {
  const void* src[17];
  unsigned short* dst[17];
  int cum4[18];
};

__global__ __launch_bounds__(256) void cvt_all(CvtArgs a, const int* __restrict__ flag, int total4) {
  const int i = blockIdx.x * 256 + threadIdx.x;
  if (i >= total4) return;
  int lo = 0, hi = 17;
  while (hi - lo > 1) {
    const int mid = (lo + hi) >> 1;
    if (i >= a.cum4[mid]) lo = mid; else hi = mid;
  }
  const int off4 = i - a.cum4[lo];
  if (*flag) {
    const u16x4* s = (const u16x4*)a.src[lo];
    *(u16x4*)&a.dst[lo][off4 * 4] = s[off4];
  } else {
    const float4* s = (const float4*)a.src[lo];
    const float4 v = s[off4];
    u16x4 o;
    o[0] = f2bf(v.x); o[1] = f2bf(v.y); o[2] = f2bf(v.z); o[3] = f2bf(v.w);
    *(u16x4*)&a.dst[lo][off4 * 4] = o;
  }
}

// ---------------------------------------------------------------------------
#define QOFF 8388608L
#define SCALE2 0.18033688011f  // (1/8) * log2(e)

template <int EPI>
__device__ __forceinline__ void gemm_epi_elem(
    unsigned short* __restrict__ out, const unsigned short* __restrict__ resid,
    int N, long gmb, int gn, const f32x4& a, float bv) {
  if constexpr (EPI == 2) {
#pragma unroll
    for (int r = 0; r < 4; ++r) {
      const long gm = gmb + r;
      out[gm * N + gn] = f2bf(a[r] + bv + bf2f(resid[gm * N + gn]));
    }
  } else if constexpr (EPI == 3) {
#pragma unroll
    for (int r = 0; r < 4; ++r)
      out[(gmb + r) * N + gn] = f2bf(fmaxf(a[r] + bv, 0.0f));
  } else {  // EPI == 4: fused QKV
    const int seg = gn >> 10;  // 0=Q, 1=K, 2=V
    const int nn = gn & 1023;
    if (seg == 0) {
#pragma unroll
      for (int r = 0; r < 4; ++r)
        out[(gmb + r) * 1024 + nn] = f2bf((a[r] + bv) * SCALE2);
    } else if (seg == 1) {
#pragma unroll
      for (int r = 0; r < 4; ++r)
        (out + QOFF)[(gmb + r) * 1024 + nn] = f2bf(a[r] + bv);
    } else {  // V^T (b,h,d,s)
      const int h = nn >> 6, d = nn & 63;
      const long b = gmb >> 11;
      const int s = (int)(gmb & 2047);
      s16x4 pv;
#pragma unroll
      for (int r = 0; r < 4; ++r) pv[r] = (short)f2bf(a[r] + bv);
      *(s16x4*)&(out + 2 * QOFF)[((b * 16 + h) * 64L + d) * 2048 + s] = pv;
    }
  }
}

// ---------------------------------------------------------------------------
// gemm8ph: C = A(MxK) * W(NxK)^T + bias.  256x256, BK=64, 512 thr, faithful
// m201 8-phase schedule (2 K-tiles per iter).  Requires K % 128 == 0.
// ---------------------------------------------------------------------------
#define GBAR asm volatile("s_barrier" ::: "memory")
#define GLGKM0 do { asm volatile("s_waitcnt lgkmcnt(0)" ::: "memory"); \
                    __builtin_amdgcn_sched_barrier(0); } while (0)

template <int EPI>
__global__ __launch_bounds__(512, 1) void gemm8ph(
    const unsigned short* __restrict__ A, const unsigned short* __restrict__ W,
    const unsigned short* __restrict__ bias, const unsigned short* __restrict__ resid,
    unsigned short* __restrict__ out, int M, int N, int K) {
  extern __shared__ unsigned short sh[];   // 2 buffers x 32768 shorts = 128 KB
  const int tid = threadIdx.x;
  const int lane = tid & 63;
  const int wave = tid >> 6;
  const int qd = lane >> 4;
  const int c = lane & 15;
  const int wvm = wave >> 2;      // 0/1 : rows [wvm*128, +128)
  const int wvn = wave & 3;       // 0..3: cols [wvn*64, +64)

  // XCD-bijective block swizzle (nwg % 8 == 0 for all our grids).
  const int nx = gridDim.x, ny = gridDim.y;
  const int nwg = nx * ny;
  int lin = blockIdx.y * nx + blockIdx.x;
  lin = (lin & 7) * (nwg >> 3) + (lin >> 3);
  const int by = lin % ny;
  const int bx = lin / ny;
  const long m0 = (long)by * 256;
  const long n0 = (long)bx * 256;

  // staging: thread owns row tid>>3 of a 64-row round, chunk tid&7; source
  // chunk XOR-swizzled so LDS dest stays linear; reads un-swizzle.
  const int srow = tid >> 3;
  const int scc = ((tid & 7) ^ (srow & 7)) * 8;
  const unsigned short* Asrc = A + (m0 + srow) * (long)K + scc;
  const unsigned short* Wsrc = W + (n0 + srow) * (long)K + scc;

  f32x4 acc[8][4] = {};
  const int NT = K >> 6;
  const int NI = K >> 7;

  // stage one 16KB half-tile (2 x gl2lds) of tile t.  which: 0=A0,1=A1,2=B0,3=B1
  auto stageHalf = [&](int t, int which) {
    unsigned short* buf = sh + (t & 1) * 32768;
    const long kof = (long)t * 64;
    if (which < 2) {
      unsigned short* d = buf + which * 8192;
      const unsigned short* s = Asrc + (long)(which * 128) * K + kof;
      gl2lds16(s, d + tid * 8);
      gl2lds16(s + (long)64 * K, d + 4096 + tid * 8);
    } else {
      const int h = which - 2;
      unsigned short* d = buf + 16384 + h * 8192;
      const unsigned short* s = Wsrc + (long)(h * 128) * K + kof;
      gl2lds16(s, d + tid * 8);
      gl2lds16(s + (long)64 * K, d + 4096 + tid * 8);
    }
  };

  auto rdA = [&](s16x8 (&af)[4][2], const unsigned short* Abase, int qm) {
#pragma unroll
    for (int mt = 0; mt < 4; ++mt)
#pragma unroll
      for (int ks = 0; ks < 2; ++ks) {
        const int lr = qm * 64 + mt * 16 + c;
        af[mt][ks] = *(const s16x8*)&Abase[wvm * 8192 + lr * 64 +
                                           (((ks * 4 + qd) ^ (c & 7)) * 8)];
      }
  };
  auto rdB = [&](s16x8 (&bf)[2][2], const unsigned short* Bbase, int qn) {
#pragma unroll
    for (int nt = 0; nt < 2; ++nt)
#pragma unroll
      for (int ks = 0; ks < 2; ++ks) {
        const int lb = (wvn & 1) * 64 + qn * 32 + nt * 16 + c;
        bf[nt][ks] = *(const s16x8*)&Bbase[(wvn >> 1) * 8192 + lb * 64 +
                                           (((ks * 4 + qd) ^ (c & 7)) * 8)];
      }
  };
  auto mfmaQ = [&](s16x8 (&af)[4][2], s16x8 (&bf)[2][2], int qm, int qn) {
    __builtin_amdgcn_s_setprio(1);
#pragma unroll
    for (int mt = 0; mt < 4; ++mt)
#pragma unroll
      for (int nt = 0; nt < 2; ++nt)
#pragma unroll
        for (int ks = 0; ks < 2; ++ks)
          acc[qm * 4 + mt][qn * 2 + nt] =
              mfma16(af[mt][ks], bf[nt][ks], acc[qm * 4 + mt][qn * 2 + nt]);
    __builtin_amdgcn_s_setprio(0);
  };

  // prologue: T0 fully (A0,A1,B0,B1) + T1 B halves = 12 loads; oldest 8 = T0.
  stageHalf(0, 0); stageHalf(0, 1); stageHalf(0, 2); stageHalf(0, 3);
  stageHalf(1, 2); stageHalf(1, 3);
  asm volatile("s_waitcnt vmcnt(4)" ::: "memory");
  GBAR;

  for (int i = 0; i < NI; ++i) {
    const int t0 = 2 * i, t1 = 2 * i + 1;
    const unsigned short* Ab0 = sh;
    const unsigned short* Bb0 = sh + 16384;
    const unsigned short* Ab1 = sh + 32768;
    const unsigned short* Bb1 = sh + 32768 + 16384;
    const bool last = (i == NI - 1);

    s16x8 af[4][2], bfa[2][2], bfb[2][2];

    // ph0: T0 q(0,0)
    rdA(af, Ab0, 0);
    rdB(bfa, Bb0, 0);
    stageHalf(t1, 0);
    GBAR; GLGKM0;
    mfmaQ(af, bfa, 0, 0);
    GBAR;

    // ph1: T0 q(0,1)
    rdB(bfb, Bb0, 1);
    stageHalf(t1, 1);
    GBAR; GLGKM0;
    mfmaQ(af, bfb, 0, 1);
    GBAR;

    // ph2: T0 q(1,1)
    rdA(af, Ab0, 1);
    if (!last) stageHalf(t0 + 2, 2);
    GBAR; GLGKM0;
    mfmaQ(af, bfb, 1, 1);
    GBAR;

    // ph3: T0 q(1,0) — no reads; vmcnt before closing barrier (T1 ready)
    if (!last) stageHalf(t0 + 2, 3);
    mfmaQ(af, bfa, 1, 0);
    if (last) asm volatile("s_waitcnt vmcnt(0)" ::: "memory");
    else      asm volatile("s_waitcnt vmcnt(4)" ::: "memory");
    GBAR;

    // ph4: T1 q(0,0)
    rdA(af, Ab1, 0);
    rdB(bfa, Bb1, 0);
    if (!last) stageHalf(t0 + 2, 0);
    GBAR; GLGKM0;
    mfmaQ(af, bfa, 0, 0);
    GBAR;

    // ph5: T1 q(0,1)
    rdB(bfb, Bb1, 1);
    if (!last) stageHalf(t0 + 2, 1);
    GBAR; GLGKM0;
    mfmaQ(af, bfb, 0, 1);
    GBAR;

    // ph6: T1 q(1,1)
    rdA(af, Ab1, 1);
    if (!last) stageHalf(t0 + 3, 2);
    GBAR; GLGKM0;
    mfmaQ(af, bfb, 1, 1);
    GBAR;

    // ph7: T1 q(1,0) — no reads; vmcnt before closing barrier (T2 ready)
    if (!last) stageHalf(t0 + 3, 3);
    mfmaQ(af, bfa, 1, 0);
    if (last) asm volatile("s_waitcnt vmcnt(0)" ::: "memory");
    else      asm volatile("s_waitcnt vmcnt(4)" ::: "memory");
    GBAR;
  }

#pragma unroll
  for (int in = 0; in < 4; ++in) {
    const int gn = (int)n0 + (wvn >> 1) * 128 + (wvn & 1) * 64 + (in >> 1) * 32 +
                   (in & 1) * 16 + c;
    const float bv = bf2f(bias[gn]);
#pragma unroll
    for (int im = 0; im < 8; ++im) {
      const long gmb = m0 + wvm * 128 + (im >> 2) * 64 + (im & 3) * 16 + qd * 4;
      gemm_epi_elem<EPI>(out, resid, N, gmb, gn, acc[im][in], bv);
    }
  }
}

// ---------------------------------------------------------------------------
// gemm2<EPI,128>: Wo/FFN2 path (R4 structure): BN=256, BK=64, 3 x 48KB
// buffers, distance-2 prefetch, one vmcnt(6)+barrier per K-step.
// ---------------------------------------------------------------------------
template <int EPI, int BM>
__global__ __launch_bounds__(512, 1) void gemm2(
    const unsigned short* __restrict__ A, const unsigned short* __restrict__ W,
    const unsigned short* __restrict__ bias, const unsigned short* __restrict__ resid,
    unsigned short* __restrict__ out, int M, int N, int K) {
  constexpr int BUFE = (BM + 256) * 64;
  extern __shared__ unsigned short sh[];

  const int tid = threadIdx.x;
  const int lane = tid & 63;
  const int wave = tid >> 6;
  const int qd = lane >> 4;
  const int c = lane & 15;
  const int wr = (wave >> 2) * (BM / 2);
  const int wc = (wave & 3) * 64;

  const int nx = gridDim.x, ny = gridDim.y;
  const int nwg = nx * ny;
  int lin = blockIdx.y * nx + blockIdx.x;
  lin = (lin & 7) * (nwg >> 3) + (lin >> 3);
  const int by = lin % ny;
  const int bx = lin / ny;
  const long m0 = (long)by * BM;
  const long n0 = (long)bx * 256;

  const int srow = tid >> 3;
  const int scc = ((tid & 7) ^ (srow & 7)) * 8;
  const unsigned short* Asrc = A + (m0 + srow) * (long)K + scc;
  const unsigned short* Wsrc = W + (n0 + srow) * (long)K + scc;
  const int lofs = tid * 8;

  f32x4 acc[BM / 32][4] = {};
  const int NT = K >> 6;

  auto stA = [&](int sel, int tt, int q) {
    gl2lds16(Asrc + (long)q * 64 * K + (long)tt * 64, sh + sel * BUFE + q * 4096 + lofs);
  };
  auto stB = [&](int sel, int tt, int q) {
    gl2lds16(Wsrc + (long)q * 64 * K + (long)tt * 64,
             sh + sel * BUFE + BM * 64 + q * 4096 + lofs);
  };

  stB(0, 0, 0); stB(0, 0, 1); stB(0, 0, 2); stB(0, 0, 3); stA(0, 0, 0); stA(0, 0, 1);
  stB(1, 1, 0); stB(1, 1, 1); stB(1, 1, 2); stB(1, 1, 3); stA(1, 1, 0); stA(1, 1, 1);

  int cur = 0;
  for (int t = 0; t < NT; ++t) {
    const unsigned short* Ab = sh + cur * BUFE;
    const unsigned short* Bb = Ab + BM * 64;

    if (t + 1 < NT) asm volatile("s_waitcnt vmcnt(6)\n\ts_barrier" ::: "memory");
    else            asm volatile("s_waitcnt vmcnt(0)\n\ts_barrier" ::: "memory");
    s16x8 bfr[4][2], af[4][2];
#pragma unroll
    for (int nt = 0; nt < 4; ++nt)
#pragma unroll
      for (int ks = 0; ks < 2; ++ks)
        bfr[nt][ks] = *(const s16x8*)&Bb[(wc + nt * 16 + c) * 64 +
                                         (((ks * 4 + qd) ^ (c & 7)) * 8)];
#pragma unroll
    for (int mt = 0; mt < 4; ++mt)
#pragma unroll
      for (int ks = 0; ks < 2; ++ks)
        af[mt][ks] = *(const s16x8*)&Ab[(wr + mt * 16 + c) * 64 +
                                        (((ks * 4 + qd) ^ (c & 7)) * 8)];
    if (t + 2 < NT) {
      const int ns = (cur >= 1) ? cur - 1 : 2;
      stB(ns, t + 2, 0); stB(ns, t + 2, 1); stB(ns, t + 2, 2); stB(ns, t + 2, 3);
      stA(ns, t + 2, 0); stA(ns, t + 2, 1);
    }
    __builtin_amdgcn_s_setprio(1);
#pragma unroll
    for (int mt = 0; mt < 4; ++mt)
#pragma unroll
      for (int nt = 0; nt < 4; ++nt)
#pragma unroll
        for (int ks = 0; ks < 2; ++ks)
          acc[mt][nt] = mfma16(af[mt][ks], bfr[nt][ks], acc[mt][nt]);
    __builtin_amdgcn_s_setprio(0);
    cur = (cur + 1 == 3) ? 0 : cur + 1;
  }

#pragma unroll
  for (int nt = 0; nt < 4; ++nt) {
    const int gn = (int)n0 + wc + nt * 16 + c;
    const float bv = bf2f(bias[gn]);
#pragma unroll
    for (int mt = 0; mt < BM / 32; ++mt) {
      const long gmb = m0 + wr + mt * 16 + qd * 4;
      gemm_epi_elem<EPI>(out, resid, N, gmb, gn, acc[mt][nt], bv);
    }
  }
}

// ---------------------------------------------------------------------------
// Flash attention (R12, unchanged). One workgroup = 256 Q rows of one (b,h).
// ---------------------------------------------------------------------------
#define ATT_S 2048

__global__ __launch_bounds__(256)
__attribute__((amdgpu_waves_per_eu(2, 2))) void attn_fwd(
    const unsigned short* __restrict__ Q, const unsigned short* __restrict__ K,
    const unsigned short* __restrict__ VT, unsigned short* __restrict__ O) {
  __shared__ unsigned short SH[32768];  // 64 KB
  unsigned short* Kb0 = SH;
  unsigned short* Kb1 = SH + 4096;
  unsigned short* Vb0 = SH + 8192;
  unsigned short* Vb1 = SH + 12288;
  unsigned short* Pl  = SH + 16384;

  const int bh = blockIdx.y;
  const int q0 = blockIdx.x * 256;
  const long b = bh >> 4;
  const int h = bh & 15;
  const unsigned short* Qg = Q + (b * 2048) * 1024 + h * 64;
  const unsigned short* Kg = K + (b * 2048) * 1024 + h * 64;
  const unsigned short* Vg = VT + (long)bh * 64 * 2048;

  const int tid = threadIdx.x;
  const int wave = tid >> 6, lane = tid & 63;
  const int qd = lane >> 4, c = lane & 15;
  const int mb = wave * 32;

  const int srow = tid >> 3;
  const int sccs = ((tid & 7) ^ (srow & 7)) * 8;

  s16x8 qf[2][2][2];
#pragma unroll
  for (int h2 = 0; h2 < 2; ++h2)
#pragma unroll
    for (int mt = 0; mt < 2; ++mt)
#pragma unroll
      for (int ks = 0; ks < 2; ++ks)
        qf[h2][mt][ks] = *(const s16x8*)&Qg[(long)(q0 + h2 * 128 + mb + mt * 16 + c) * 1024 +
                                            ks * 32 + qd * 8];

  s16x8 ones;
#pragma unroll
  for (int i = 0; i < 8; ++i) ones[i] = (short)0x3F80;

  f32x4 oacc[2][4][2] = {};
  f32x4 lacc[2][2] = {};

  gl2lds16(Kg + (long)srow * 1024 + sccs, &Kb0[tid * 8]);
  gl2lds16(Kg + (long)(srow + 32) * 1024 + sccs, &Kb0[(256 + tid) * 8]);
  gl2lds16(Vg + (long)srow * 2048 + sccs, &Vb0[tid * 8]);
  gl2lds16(Vg + (long)(srow + 32) * 2048 + sccs, &Vb0[(256 + tid) * 8]);

  for (int it = 0; it < 32; ++it) {
    const int p = it & 1;
    unsigned short* Kc = p ? Kb1 : Kb0;
    unsigned short* Vc = p ? Vb1 : Vb0;
    unsigned short* Kn = p ? Kb0 : Kb1;
    unsigned short* Vn = p ? Vb0 : Vb1;
    const int kvn = (it < 31) ? (it + 1) * 64 : 31 * 64;
    gl2lds16(Kg + (long)(kvn + srow) * 1024 + sccs, &Kn[tid * 8]);
    gl2lds16(Kg + (long)(kvn + srow + 32) * 1024 + sccs, &Kn[(256 + tid) * 8]);
    gl2lds16(Vg + (long)srow * 2048 + kvn + sccs, &Vn[tid * 8]);
    gl2lds16(Vg + (long)(srow + 32) * 2048 + kvn + sccs, &Vn[(256 + tid) * 8]);

    asm volatile("s_waitcnt vmcnt(4)\n\ts_barrier" ::: "memory");

    f32x4 sacc[2][4][2] = {};
#pragma unroll
    for (int ks = 0; ks < 2; ++ks) {
      const int ch = ((ks * 4 + qd) ^ (c & 7)) * 8;
      s16x8 kf[4];
#pragma unroll
      for (int tt = 0; tt < 4; ++tt)
        kf[tt] = *(const s16x8*)&Kc[(tt * 16 + c) * 64 + ch];
#pragma unroll
      for (int h2 = 0; h2 < 2; ++h2)
#pragma unroll
        for (int mt = 0; mt < 2; ++mt)
#pragma unroll
          for (int tt = 0; tt < 4; ++tt)
            sacc[h2][tt][mt] = mfma16(kf[tt], qf[h2][mt][ks], sacc[h2][tt][mt]);
    }

#pragma unroll
    for (int h2 = 0; h2 < 2; ++h2) {
      unsigned short* Ph = Pl + h2 * 8192;
#pragma unroll
      for (int mt = 0; mt < 2; ++mt) {
        const int ml = mb + mt * 16 + c;
#pragma unroll
        for (int tt = 0; tt < 4; ++tt) {
          unsigned int pk[2];
          pk[0] = pkbf_trunc(__builtin_amdgcn_exp2f(sacc[h2][tt][mt][0]),
                             __builtin_amdgcn_exp2f(sacc[h2][tt][mt][1]));
          pk[1] = pkbf_trunc(__builtin_amdgcn_exp2f(sacc[h2][tt][mt][2]),
                             __builtin_amdgcn_exp2f(sacc[h2][tt][mt][3]));
          const int chw = ((tt * 2 + (qd >> 1)) ^ (ml & 7)) * 8 + (qd & 1) * 4;
          *(uint2*)&Ph[ml * 64 + chw] = *(uint2*)pk;
        }
      }
    }
    asm volatile("s_waitcnt lgkmcnt(0)" ::: "memory");

#pragma unroll
    for (int ks = 0; ks < 2; ++ks) {
      const int vch = ((ks * 4 + qd) ^ (c & 7)) * 8;
      s16x8 vf[4];
#pragma unroll
      for (int dt = 0; dt < 4; ++dt)
        vf[dt] = *(const s16x8*)&Vc[(dt * 16 + c) * 64 + vch];
#pragma unroll
      for (int h2 = 0; h2 < 2; ++h2) {
        const unsigned short* Ph = Pl + h2 * 8192;
        s16x8 pf[2];
#pragma unroll
        for (int mt = 0; mt < 2; ++mt) {
          const int pr = mb + mt * 16 + c;
          pf[mt] = *(const s16x8*)&Ph[pr * 64 + (((ks * 4 + qd) ^ (pr & 7)) * 8)];
        }
#pragma unroll
        for (int mt = 0; mt < 2; ++mt) {
#pragma unroll
          for (int dt = 0; dt < 4; ++dt)
            oacc[h2][dt][mt] = mfma16(vf[dt], pf[mt], oacc[h2][dt][mt]);
          lacc[h2][mt] = mfma16(ones, pf[mt], lacc[h2][mt]);
        }
      }
    }

    asm volatile("s_barrier" ::: "memory");
  }

#pragma unroll
  for (int h2 = 0; h2 < 2; ++h2)
#pragma unroll
    for (int mt = 0; mt < 2; ++mt) {
      const float inv = 1.0f / lacc[h2][mt][0];
      const int s = q0 + h2 * 128 + mb + mt * 16 + c;
      const long ob = (b * (long)ATT_S + s) * 1024L + h * 64;
#pragma unroll
      for (int dt = 0; dt < 4; ++dt) {
        s16x4 ov;
#pragma unroll
        for (int r = 0; r < 4; ++r) ov[r] = (short)f2bf(oacc[h2][dt][mt][r] * inv);
        *(s16x4*)&O[ob + dt * 16 + qd * 4] = ov;
      }
    }
}

// ---------------------------------------------------------------------------
template <bool FINAL>
__global__ __launch_bounds__(256) void norm_affine(
    const unsigned short* __restrict__ X, const unsigned short* __restrict__ av,
    const unsigned short* __restrict__ bv, void* __restrict__ outv,
    const int* __restrict__ flag) {
  const int row = blockIdx.x;
  const int s = row & 2047;
  const unsigned short* xr = X + (long)row * 1024;
  const int tid = threadIdx.x;
  const u16x4 u = *(const u16x4*)&xr[tid * 4];
  float v[4];
  float s1 = 0.f, s2 = 0.f;
#pragma unroll
  for (int i = 0; i < 4; ++i) {
    v[i] = bf2f(u[i]);
    s1 += v[i];
    s2 += v[i] * v[i];
  }
#pragma unroll
  for (int off = 32; off >= 1; off >>= 1) {
    s1 += __shfl_xor(s1, off);
    s2 += __shfl_xor(s2, off);
  }
  __shared__ float red[8];
  const int wave = tid >> 6, lane = tid & 63;
  if (lane == 0) {
    red[wave * 2] = s1;
    red[wave * 2 + 1] = s2;
  }
  __syncthreads();
  s1 = red[0] + red[2] + red[4] + red[6];
  s2 = red[1] + red[3] + red[5] + red[7];
  const float mean = s1 * (1.0f / 1024.0f);
  const float var = fmaxf(s2 * (1.0f / 1024.0f) - mean * mean, 0.0f);
  const float rstd = rsqrtf(var + 1e-5f);
  const float aa = bf2f(av[s]), bb = bf2f(bv[s]);
  float o[4];
#pragma unroll
  for (int i = 0; i < 4; ++i) o[i] = aa * (v[i] - mean) * rstd + bb;
  bool as_bf16 = true;
  if constexpr (FINAL) as_bf16 = (*flag != 0);
  if (as_bf16) {
    u16x4 ob;
#pragma unroll
    for (int i = 0; i < 4; ++i) ob[i] = f2bf(o[i]);
    *(u16x4*)&((unsigned short*)outv)[(long)row * 1024 + tid * 4] = ob;
  } else {
    float4 of = {o[0], o[1], o[2], o[3]};
    *(float4*)&((float*)outv)[(long)row * 1024 + tid * 4] = of;
  }
}

// ---------------------------------------------------------------------------
extern "C" void kernel_launch(void* const* d_in, const int* in_sizes, int n_in,
                              void* d_out, int out_size, void* d_ws, size_t ws_size,
                              hipStream_t stream) {
  char* ws = (char*)d_ws;
  const size_t SZ = 8192ull * 1024 * 2;
  const size_t WSZ = 1024ull * 1024 * 2;

  unsigned short* xb   = (unsigned short*)(ws);
  unsigned short* qb   = (unsigned short*)(ws + SZ);   // qb,kb,vtb contiguous
  unsigned short* kb   = (unsigned short*)(ws + 2 * SZ);
  unsigned short* vtb  = (unsigned short*)(ws + 3 * SZ);
  unsigned short* attn = (unsigned short*)(ws + 4 * SZ);
  unsigned short* hb   = (unsigned short*)(ws + 5 * SZ);
  unsigned short* r1   = qb;
  unsigned short* ffb  = kb;
  unsigned short* r2   = attn;

  char* wreg = ws + 6 * SZ;
  unsigned short* wqb = (unsigned short*)(wreg);
  unsigned short* w1b = (unsigned short*)(wreg + 4 * WSZ);
  unsigned short* w2b = (unsigned short*)(wreg + 6 * WSZ);
  unsigned short* wob = (unsigned short*)(wreg + 3 * WSZ);
  unsigned short* smal = (unsigned short*)(wreg + 8 * WSZ);
  unsigned short* bqb = smal;
  unsigned short* bkb = smal + 1024;
  unsigned short* bvb = smal + 2048;
  unsigned short* bob = smal + 3072;
  unsigned short* b1b = smal + 4096;
  unsigned short* b2b = smal + 6144;
  unsigned short* a1b = smal + 7168;
  unsigned short* g1b = smal + 9216;
  unsigned short* a2b = smal + 11264;
  unsigned short* g2b = smal + 13312;
  int* flag = (int*)(wreg + 8 * WSZ + 64 * 1024);

  CvtArgs ca;
  unsigned short* wkb = wqb + 1024 * 1024;
  unsigned short* wvb = wqb + 2 * 1024 * 1024;
  unsigned short* dsts[17] = {xb, wqb, bqb, wkb, bkb, wvb, bvb, wob, bob,
                              a1b, g1b, w1b, b1b, w2b, b2b, a2b, g2b};
  ca.cum4[0] = 0;
  for (int i = 0; i < 17; ++i) {
    ca.src[i] = d_in[i];
    ca.dst[i] = dsts[i];
    ca.cum4[i + 1] = ca.cum4[i] + in_sizes[i] / 4;
  }
  const int total4 = ca.cum4[17];

  static bool attr_set = false;
  if (!attr_set) {
    attr_set = true;
    hipFuncSetAttribute(reinterpret_cast<const void*>(gemm8ph<4>),
                        hipFuncAttributeMaxDynamicSharedMemorySize, 131072);
    hipFuncSetAttribute(reinterpret_cast<const void*>(gemm8ph<3>),
                        hipFuncAttributeMaxDynamicSharedMemorySize, 131072);
    hipFuncSetAttribute(reinterpret_cast<const void*>(gemm2<2, 128>),
                        hipFuncAttributeMaxDynamicSharedMemorySize, 147456);
  }

  dim3 blk(256);
  dim3 blk512(512);
  detect_dtype<<<1, blk, 0, stream>>>((const unsigned int*)d_in[0], flag);
  cvt_all<<<(total4 + 255) / 256, blk, 0, stream>>>(ca, flag, total4);

  gemm8ph<4><<<dim3(12, 32), blk512, 131072, stream>>>(xb, wqb, bqb, nullptr, qb, 8192, 3072, 1024);
  attn_fwd<<<dim3(8, 64), blk, 0, stream>>>(qb, kb, vtb, attn);
  gemm2<2, 128><<<dim3(4, 64), blk512, 147456, stream>>>(attn, wob, bob, xb, r1, 8192, 1024, 1024);
  norm_affine<false><<<8192, blk, 0, stream>>>(r1, a1b, g1b, hb, nullptr);
  gemm8ph<3><<<dim3(8, 32), blk512, 131072, stream>>>(hb, w1b, b1b, nullptr, ffb, 8192, 2048, 1024);
  gemm2<2, 128><<<dim3(4, 64), blk512, 147456, stream>>>(ffb, w2b, b2b, hb, r2, 8192, 1024, 2048);
  norm_affine<true><<<8192, blk, 0, stream>>>(r2, a2b, g2b, d_out, flag);
}

// Round 7
// 416.921 us; speedup vs baseline: 1.0268x; 1.0268x over previous
//
#include <hip/hip_runtime.h>

// ---------------------------------------------------------------------------
// TransformerBlock (B=4,S=2048,E=1024,H=16,Dh=64), fp32 (or bf16) in, fp32
// (or bf16) out — dtype auto-detected; all compute in bf16 MFMA w/ fp32 accum.
// Pipeline: cvt-to-bf16 -> fused QKV gemm -> flash attn -> Wo gemm (+x) ->
//           norm1 -> FFN1 (relu) -> FFN2 (+h) -> norm2 -> out
// R14 = best-of-each revert + QKV grid-quantization fix:
//   - GEMMs: R4/R11 dedup gemm2 (24 ds_read/64 MFMA at BM=256; 2-phase,
//     counted waits).  Schedule experiments (snake R5, 8-phase R6) measured
//     <= R4 on this problem (short K=1024: 8 iters can't amortize the deep
//     pipeline) — abandoned.
//   - QKV now gemm2<4,128>, grid (12,64)=768 blocks = 3 clean rounds/CU
//     (was 384 blocks = 1.5 rounds -> 25% chip-idle quantization waste).
//   - FFN1 gemm2<3,256> (256 blocks, 1 round).  Wo/FFN2 gemm2<2,128>.
//   - attn: R4 version (85.8us measured vs 89.2 for the fused-halves R12).
// ---------------------------------------------------------------------------

typedef __attribute__((ext_vector_type(8))) short s16x8;
typedef __attribute__((ext_vector_type(4))) short s16x4;
typedef __attribute__((ext_vector_type(4))) unsigned short u16x4;
typedef __attribute__((ext_vector_type(4))) float f32x4;

__device__ __forceinline__ float bf2f(unsigned short u) {
  unsigned int v = ((unsigned int)u) << 16;
  return __builtin_bit_cast(float, v);
}
__device__ __forceinline__ unsigned short f2bf(float f) {
  unsigned int u = __builtin_bit_cast(unsigned int, f);
  u += 0x7fffu + ((u >> 16) & 1u);   // RNE
  return (unsigned short)(u >> 16);
}
// pack two f32 -> two bf16 (truncate) in one v_perm_b32
__device__ __forceinline__ unsigned int pkbf_trunc(float f0, float f1) {
  return __builtin_amdgcn_perm(__builtin_bit_cast(unsigned int, f1),
                               __builtin_bit_cast(unsigned int, f0), 0x07060302u);
}
__device__ __forceinline__ f32x4 mfma16(s16x8 a, s16x8 b, f32x4 c) {
  return __builtin_amdgcn_mfma_f32_16x16x32_bf16(a, b, c, 0, 0, 0);
}
__device__ __forceinline__ void gl2lds16(const unsigned short* g, unsigned short* l) {
  __builtin_amdgcn_global_load_lds(
      (const __attribute__((address_space(1))) unsigned int*)(g),
      (__attribute__((address_space(3))) unsigned int*)(l), 16, 0, 0);
}

// ---------------------------------------------------------------------------
__global__ void detect_dtype(const unsigned int* __restrict__ x, int* __restrict__ flag) {
  const int tid = threadIdx.x;
  int cnt = 0;
  for (int i = tid; i < 2048; i += 256) {
    const unsigned e = (x[i] >> 7) & 0xFF;
    cnt += (e >= 100 && e <= 150) ? 1 : 0;
  }
#pragma unroll
  for (int off = 32; off >= 1; off >>= 1) cnt += __shfl_xor(cnt, off);
  __shared__ int red[4];
  if ((tid & 63) == 0) red[tid >> 6] = cnt;
  __syncthreads();
  if (tid == 0) *flag = ((red[0] + red[1] + red[2] + red[3]) > 1536) ? 1 : 0;
}

// ---------------------------------------------------------------------------
struct CvtArgs {
  const void* src[17];
  unsigned short* dst[17];
  int cum4[18];
};

__global__ __launch_bounds__(256) void cvt_all(CvtArgs a, const int* __restrict__ flag, int total4) {
  const int i = blockIdx.x * 256 + threadIdx.x;
  if (i >= total4) return;
  int lo = 0, hi = 17;
  while (hi - lo > 1) {
    const int mid = (lo + hi) >> 1;
    if (i >= a.cum4[mid]) lo = mid; else hi = mid;
  }
  const int off4 = i - a.cum4[lo];
  if (*flag) {
    const u16x4* s = (const u16x4*)a.src[lo];
    *(u16x4*)&a.dst[lo][off4 * 4] = s[off4];
  } else {
    const float4* s = (const float4*)a.src[lo];
    const float4 v = s[off4];
    u16x4 o;
    o[0] = f2bf(v.x); o[1] = f2bf(v.y); o[2] = f2bf(v.z); o[3] = f2bf(v.w);
    *(u16x4*)&a.dst[lo][off4 * 4] = o;
  }
}

// ---------------------------------------------------------------------------
// GEMM: C = A(MxK) * W(NxK)^T + bias.  BN=256, BK=64, 512 threads,
// 8 waves 2Mx4N (per-wave (BM/2)x64).
// EPI 2: += resid. EPI 3: relu. EPI 4: fused QKV split (Q scaled, V^T scatter).
// ---------------------------------------------------------------------------
#define QOFF 8388608L
#define SCALE2 0.18033688011f  // (1/8) * log2(e)

template <int EPI, int BM>
__global__ __launch_bounds__(512, 1) void gemm2(
    const unsigned short* __restrict__ A, const unsigned short* __restrict__ W,
    const unsigned short* __restrict__ bias, const unsigned short* __restrict__ resid,
    unsigned short* __restrict__ out, int M, int N, int K) {
  constexpr int NBUF = (BM == 256) ? 2 : 3;
  constexpr int BUFE = (BM + 256) * 64;   // shorts per buffer
  extern __shared__ unsigned short sh[];

  const int tid = threadIdx.x;
  const int lane = tid & 63;
  const int wave = tid >> 6;
  const int qd = lane >> 4;
  const int c = lane & 15;
  const int wr = (wave >> 2) * (BM / 2);
  const int wc = (wave & 3) * 64;

  // XCD-bijective block swizzle (nwg % 8 == 0 for all our grids).
  const int nx = gridDim.x, ny = gridDim.y;
  const int nwg = nx * ny;
  int lin = blockIdx.y * nx + blockIdx.x;
  lin = (lin & 7) * (nwg >> 3) + (lin >> 3);
  const int by = lin % ny;            // M varies fastest within an XCD chunk
  const int bx = lin / ny;            // -> B-panel resident per XCD-L2
  const long m0 = (long)by * BM;
  const long n0 = (long)bx * 256;

  // staging: thread owns row (tid>>3) of a 64-row quarter, chunk tid&7,
  // source col XOR-swizzled so LDS dest stays linear; reads unswizzle.
  const int srow = tid >> 3;
  const int scc = ((tid & 7) ^ (srow & 7)) * 8;
  const unsigned short* Asrc = A + (m0 + srow) * (long)K + scc;
  const unsigned short* Wsrc = W + (n0 + srow) * (long)K + scc;
  const int lofs = tid * 8;

  f32x4 acc[BM / 32][4] = {};

  const int NT = K >> 6;

  auto stA = [&](int sel, int tt, int q) {
    gl2lds16(Asrc + (long)q * 64 * K + (long)tt * 64, sh + sel * BUFE + q * 4096 + lofs);
  };
  auto stB = [&](int sel, int tt, int q) {
    gl2lds16(Wsrc + (long)q * 64 * K + (long)tt * 64,
             sh + sel * BUFE + BM * 64 + q * 4096 + lofs);
  };

  // prologue (issue order = age order for the counted waits)
  if constexpr (BM == 256) {
    stB(0, 0, 0); stB(0, 0, 1); stB(0, 0, 2); stB(0, 0, 3);
    stA(0, 0, 0); stA(0, 0, 2); stA(0, 0, 1); stA(0, 0, 3);
  } else {
    stB(0, 0, 0); stB(0, 0, 1); stB(0, 0, 2); stB(0, 0, 3); stA(0, 0, 0); stA(0, 0, 1);
    stB(1, 1, 0); stB(1, 1, 1); stB(1, 1, 2); stB(1, 1, 3); stA(1, 1, 0); stA(1, 1, 1);
  }

  int cur = 0;
  for (int t = 0; t < NT; ++t) {
    const unsigned short* Ab = sh + cur * BUFE;
    const unsigned short* Bb = Ab + BM * 64;

    if constexpr (BM == 256) {
      const bool dost = (t + 1 < NT);
      const int ns = cur ^ 1;
      // B,A-q0,A-q2 of tile t landed; its A-q1,A-q3 (newest 2) still in flight
      asm volatile("s_waitcnt vmcnt(2)\n\ts_barrier" ::: "memory");
      s16x8 bfr[4][2], af[4][2];
#pragma unroll
      for (int nt = 0; nt < 4; ++nt)
#pragma unroll
        for (int ks = 0; ks < 2; ++ks)
          bfr[nt][ks] = *(const s16x8*)&Bb[(wc + nt * 16 + c) * 64 +
                                           (((ks * 4 + qd) ^ (c & 7)) * 8)];
#pragma unroll
      for (int mt = 0; mt < 4; ++mt)
#pragma unroll
        for (int ks = 0; ks < 2; ++ks)
          af[mt][ks] = *(const s16x8*)&Ab[(wr + mt * 16 + c) * 64 +
                                          (((ks * 4 + qd) ^ (c & 7)) * 8)];
      if (dost) { stB(ns, t + 1, 0); stB(ns, t + 1, 1); stB(ns, t + 1, 2); stB(ns, t + 1, 3); }
      __builtin_amdgcn_s_setprio(1);
#pragma unroll
      for (int mt = 0; mt < 4; ++mt)
#pragma unroll
        for (int nt = 0; nt < 4; ++nt)
#pragma unroll
          for (int ks = 0; ks < 2; ++ks)
            acc[mt][nt] = mfma16(af[mt][ks], bfr[nt][ks], acc[mt][nt]);
      __builtin_amdgcn_s_setprio(0);
      // drain tile t's A-q1/A-q3 (leave t+1's 4 B loads in flight)
      if (dost) asm volatile("s_waitcnt vmcnt(4)\n\ts_barrier" ::: "memory");
      else      asm volatile("s_waitcnt vmcnt(0)\n\ts_barrier" ::: "memory");
#pragma unroll
      for (int mt = 0; mt < 4; ++mt)
#pragma unroll
        for (int ks = 0; ks < 2; ++ks)
          af[mt][ks] = *(const s16x8*)&Ab[(wr + 64 + mt * 16 + c) * 64 +
                                          (((ks * 4 + qd) ^ (c & 7)) * 8)];
      if (dost) { stA(ns, t + 1, 0); stA(ns, t + 1, 2); stA(ns, t + 1, 1); stA(ns, t + 1, 3); }
      __builtin_amdgcn_s_setprio(1);
#pragma unroll
      for (int mt = 0; mt < 4; ++mt)
#pragma unroll
        for (int nt = 0; nt < 4; ++nt)
#pragma unroll
          for (int ks = 0; ks < 2; ++ks)
            acc[4 + mt][nt] = mfma16(af[mt][ks], bfr[nt][ks], acc[4 + mt][nt]);
      __builtin_amdgcn_s_setprio(0);
    } else {
      // tile t landed; tile t+1's 6 loads stay in flight
      if (t + 1 < NT) asm volatile("s_waitcnt vmcnt(6)\n\ts_barrier" ::: "memory");
      else            asm volatile("s_waitcnt vmcnt(0)\n\ts_barrier" ::: "memory");
      s16x8 bfr[4][2], af[4][2];
#pragma unroll
      for (int nt = 0; nt < 4; ++nt)
#pragma unroll
        for (int ks = 0; ks < 2; ++ks)
          bfr[nt][ks] = *(const s16x8*)&Bb[(wc + nt * 16 + c) * 64 +
                                           (((ks * 4 + qd) ^ (c & 7)) * 8)];
#pragma unroll
      for (int mt = 0; mt < 4; ++mt)
#pragma unroll
        for (int ks = 0; ks < 2; ++ks)
          af[mt][ks] = *(const s16x8*)&Ab[(wr + mt * 16 + c) * 64 +
                                          (((ks * 4 + qd) ^ (c & 7)) * 8)];
      if (t + 2 < NT) {
        const int ns = (cur >= 1) ? cur - 1 : 2;   // (cur+2)%3
        stB(ns, t + 2, 0); stB(ns, t + 2, 1); stB(ns, t + 2, 2); stB(ns, t + 2, 3);
        stA(ns, t + 2, 0); stA(ns, t + 2, 1);
      }
      __builtin_amdgcn_s_setprio(1);
#pragma unroll
      for (int mt = 0; mt < 4; ++mt)
#pragma unroll
        for (int nt = 0; nt < 4; ++nt)
#pragma unroll
          for (int ks = 0; ks < 2; ++ks)
            acc[mt][nt] = mfma16(af[mt][ks], bfr[nt][ks], acc[mt][nt]);
      __builtin_amdgcn_s_setprio(0);
    }
    cur = (cur + 1 == NBUF) ? 0 : cur + 1;
  }

#pragma unroll
  for (int nt = 0; nt < 4; ++nt) {
    const int gn = (int)n0 + wc + nt * 16 + c;
    const float bv = bf2f(bias[gn]);
#pragma unroll
    for (int mt = 0; mt < BM / 32; ++mt) {
      const long gmb = m0 + wr + mt * 16 + qd * 4;
      if constexpr (EPI == 2) {
#pragma unroll
        for (int r = 0; r < 4; ++r) {
          const long gm = gmb + r;
          const float v = acc[mt][nt][r] + bv + bf2f(resid[gm * N + gn]);
          out[gm * N + gn] = f2bf(v);
        }
      } else if constexpr (EPI == 3) {
#pragma unroll
        for (int r = 0; r < 4; ++r) {
          const long gm = gmb + r;
          float v = acc[mt][nt][r] + bv;
          v = fmaxf(v, 0.0f);
          out[gm * N + gn] = f2bf(v);
        }
      } else {  // EPI == 4: fused QKV
        const int seg = gn >> 10;       // 0=Q, 1=K, 2=V  (uniform per block)
        const int nn = gn & 1023;
        if (seg == 0) {                 // Q plain (s,1024), pre-scaled
#pragma unroll
          for (int r = 0; r < 4; ++r)
            out[(gmb + r) * 1024 + nn] = f2bf((acc[mt][nt][r] + bv) * SCALE2);
        } else if (seg == 1) {          // K plain (s,1024)
#pragma unroll
          for (int r = 0; r < 4; ++r)
            (out + QOFF)[(gmb + r) * 1024 + nn] = f2bf(acc[mt][nt][r] + bv);
        } else {                        // V^T (b,h,d,s)
          const int h = nn >> 6, d = nn & 63;
          const long b = gmb >> 11;
          const int s = (int)(gmb & 2047);
          s16x4 pv;
#pragma unroll
          for (int r = 0; r < 4; ++r) pv[r] = (short)f2bf(acc[mt][nt][r] + bv);
          *(s16x4*)&(out + 2 * QOFF)[((b * 16 + h) * 64L + d) * 2048 + s] = pv;
        }
      }
    }
  }
}

// ---------------------------------------------------------------------------
// Flash attention (R4/R7 version — best measured). One workgroup = 256 Q rows
// of one (b,h).  KV tile = 64 rows, double-buffered, raw s_barrier +
// s_waitcnt vmcnt(4).  LDS 48 KB.
// ---------------------------------------------------------------------------
#define ATT_S 2048

__global__ __launch_bounds__(256)
__attribute__((amdgpu_waves_per_eu(2, 2))) void attn_fwd(
    const unsigned short* __restrict__ Q, const unsigned short* __restrict__ K,
    const unsigned short* __restrict__ VT, unsigned short* __restrict__ O) {
  __shared__ unsigned short SH[24576];  // 48 KB
  unsigned short* Kb0 = SH;             // [t][d] 64x64 swizzled
  unsigned short* Kb1 = SH + 4096;
  unsigned short* Vb0 = SH + 8192;      // [d][t] 64x64 swizzled
  unsigned short* Vb1 = SH + 12288;
  unsigned short* Pl  = SH + 16384;     // [m][t] 128x64 swizzled

  const int bh = blockIdx.y;
  const int q0 = blockIdx.x * 256;
  const long b = bh >> 4;
  const int h = bh & 15;
  const unsigned short* Qg = Q + (b * 2048) * 1024 + h * 64;
  const unsigned short* Kg = K + (b * 2048) * 1024 + h * 64;
  const unsigned short* Vg = VT + (long)bh * 64 * 2048;

  const int tid = threadIdx.x;
  const int wave = tid >> 6, lane = tid & 63;
  const int qd = lane >> 4, c = lane & 15;
  const int mb = wave * 32;

  const int srow = tid >> 3;
  const int sccs = ((tid & 7) ^ (srow & 7)) * 8;

  s16x8 qf[2][2][2];  // [half][mt][ks]
#pragma unroll
  for (int h2 = 0; h2 < 2; ++h2)
#pragma unroll
    for (int mt = 0; mt < 2; ++mt)
#pragma unroll
      for (int ks = 0; ks < 2; ++ks)
        qf[h2][mt][ks] = *(const s16x8*)&Qg[(long)(q0 + h2 * 128 + mb + mt * 16 + c) * 1024 +
                                            ks * 32 + qd * 8];

  s16x8 ones;
#pragma unroll
  for (int i = 0; i < 8; ++i) ones[i] = (short)0x3F80;

  f32x4 oacc[2][4][2] = {};  // [half][dt][mt]
  f32x4 lacc[2][2] = {};     // [half][mt]

  // preload tile 0
  gl2lds16(Kg + (long)srow * 1024 + sccs, &Kb0[tid * 8]);
  gl2lds16(Kg + (long)(srow + 32) * 1024 + sccs, &Kb0[(256 + tid) * 8]);
  gl2lds16(Vg + (long)srow * 2048 + sccs, &Vb0[tid * 8]);
  gl2lds16(Vg + (long)(srow + 32) * 2048 + sccs, &Vb0[(256 + tid) * 8]);

  for (int it = 0; it < 32; ++it) {
    const int p = it & 1;
    unsigned short* Kc = p ? Kb1 : Kb0;
    unsigned short* Vc = p ? Vb1 : Vb0;
    unsigned short* Kn = p ? Kb0 : Kb1;
    unsigned short* Vn = p ? Vb0 : Vb1;
    const int kvn = (it < 31) ? (it + 1) * 64 : 31 * 64;  // clamp keeps vmcnt math uniform
    gl2lds16(Kg + (long)(kvn + srow) * 1024 + sccs, &Kn[tid * 8]);
    gl2lds16(Kg + (long)(kvn + srow + 32) * 1024 + sccs, &Kn[(256 + tid) * 8]);
    gl2lds16(Vg + (long)srow * 2048 + kvn + sccs, &Vn[tid * 8]);
    gl2lds16(Vg + (long)(srow + 32) * 2048 + kvn + sccs, &Vn[(256 + tid) * 8]);

    // tile `it` fully landed; tile it+1's 4 loads stay in flight
    asm volatile("s_waitcnt vmcnt(4)\n\ts_barrier" ::: "memory");

#pragma unroll
    for (int h2 = 0; h2 < 2; ++h2) {
      f32x4 sacc[4][2] = {};
#pragma unroll
      for (int ks = 0; ks < 2; ++ks) {
        const int ch = ((ks * 4 + qd) ^ (c & 7)) * 8;
        s16x8 kf[4];
#pragma unroll
        for (int tt = 0; tt < 4; ++tt)
          kf[tt] = *(const s16x8*)&Kc[(tt * 16 + c) * 64 + ch];
#pragma unroll
        for (int mt = 0; mt < 2; ++mt)
#pragma unroll
          for (int tt = 0; tt < 4; ++tt)
            sacc[tt][mt] = mfma16(kf[tt], qf[h2][mt][ks], sacc[tt][mt]);
      }

      // exp2 + pack into wave-private P rows (8-chunk XOR swizzle, row len 64)
#pragma unroll
      for (int mt = 0; mt < 2; ++mt) {
        const int ml = mb + mt * 16 + c;
#pragma unroll
        for (int tt = 0; tt < 4; ++tt) {
          unsigned int pk[2];
          pk[0] = pkbf_trunc(__builtin_amdgcn_exp2f(sacc[tt][mt][0]),
                             __builtin_amdgcn_exp2f(sacc[tt][mt][1]));
          pk[1] = pkbf_trunc(__builtin_amdgcn_exp2f(sacc[tt][mt][2]),
                             __builtin_amdgcn_exp2f(sacc[tt][mt][3]));
          const int chw = ((tt * 2 + (qd >> 1)) ^ (ml & 7)) * 8 + (qd & 1) * 4;
          *(uint2*)&Pl[ml * 64 + chw] = *(uint2*)pk;
        }
      }
      asm volatile("s_waitcnt lgkmcnt(0)" ::: "memory");  // own-wave P visible

#pragma unroll
      for (int ks = 0; ks < 2; ++ks) {
        const int vch = ((ks * 4 + qd) ^ (c & 7)) * 8;
        s16x8 vf[4], pf[2];
#pragma unroll
        for (int dt = 0; dt < 4; ++dt)
          vf[dt] = *(const s16x8*)&Vc[(dt * 16 + c) * 64 + vch];
#pragma unroll
        for (int mt = 0; mt < 2; ++mt) {
          const int pr = mb + mt * 16 + c;
          pf[mt] = *(const s16x8*)&Pl[pr * 64 + (((ks * 4 + qd) ^ (pr & 7)) * 8)];
        }
#pragma unroll
        for (int mt = 0; mt < 2; ++mt) {
#pragma unroll
          for (int dt = 0; dt < 4; ++dt)
            oacc[h2][dt][mt] = mfma16(vf[dt], pf[mt], oacc[h2][dt][mt]);
          lacc[h2][mt] = mfma16(ones, pf[mt], lacc[h2][mt]);
        }
      }
    }

    // all waves done reading this buffer before next iter's prefetch hits it
    asm volatile("s_barrier" ::: "memory");
  }

#pragma unroll
  for (int h2 = 0; h2 < 2; ++h2)
#pragma unroll
    for (int mt = 0; mt < 2; ++mt) {
      const float inv = 1.0f / lacc[h2][mt][0];
      const int s = q0 + h2 * 128 + mb + mt * 16 + c;
      const long ob = (b * (long)ATT_S + s) * 1024L + h * 64;
#pragma unroll
      for (int dt = 0; dt < 4; ++dt) {
        s16x4 ov;
#pragma unroll
        for (int r = 0; r < 4; ++r) ov[r] = (short)f2bf(oacc[h2][dt][mt][r] * inv);
        *(s16x4*)&O[ob + dt * 16 + qd * 4] = ov;
      }
    }
}

// ---------------------------------------------------------------------------
template <bool FINAL>
__global__ __launch_bounds__(256) void norm_affine(
    const unsigned short* __restrict__ X, const unsigned short* __restrict__ av,
    const unsigned short* __restrict__ bv, void* __restrict__ outv,
    const int* __restrict__ flag) {
  const int row = blockIdx.x;
  const int s = row & 2047;
  const unsigned short* xr = X + (long)row * 1024;
  const int tid = threadIdx.x;
  const u16x4 u = *(const u16x4*)&xr[tid * 4];
  float v[4];
  float s1 = 0.f, s2 = 0.f;
#pragma unroll
  for (int i = 0; i < 4; ++i) {
    v[i] = bf2f(u[i]);
    s1 += v[i];
    s2 += v[i] * v[i];
  }
#pragma unroll
  for (int off = 32; off >= 1; off >>= 1) {
    s1 += __shfl_xor(s1, off);
    s2 += __shfl_xor(s2, off);
  }
  __shared__ float red[8];
  const int wave = tid >> 6, lane = tid & 63;
  if (lane == 0) {
    red[wave * 2] = s1;
    red[wave * 2 + 1] = s2;
  }
  __syncthreads();
  s1 = red[0] + red[2] + red[4] + red[6];
  s2 = red[1] + red[3] + red[5] + red[7];
  const float mean = s1 * (1.0f / 1024.0f);
  const float var = fmaxf(s2 * (1.0f / 1024.0f) - mean * mean, 0.0f);
  const float rstd = rsqrtf(var + 1e-5f);
  const float aa = bf2f(av[s]), bb = bf2f(bv[s]);
  float o[4];
#pragma unroll
  for (int i = 0; i < 4; ++i) o[i] = aa * (v[i] - mean) * rstd + bb;
  bool as_bf16 = true;
  if constexpr (FINAL) as_bf16 = (*flag != 0);
  if (as_bf16) {
    u16x4 ob;
#pragma unroll
    for (int i = 0; i < 4; ++i) ob[i] = f2bf(o[i]);
    *(u16x4*)&((unsigned short*)outv)[(long)row * 1024 + tid * 4] = ob;
  } else {
    float4 of = {o[0], o[1], o[2], o[3]};
    *(float4*)&((float*)outv)[(long)row * 1024 + tid * 4] = of;
  }
}

// ---------------------------------------------------------------------------
extern "C" void kernel_launch(void* const* d_in, const int* in_sizes, int n_in,
                              void* d_out, int out_size, void* d_ws, size_t ws_size,
                              hipStream_t stream) {
  char* ws = (char*)d_ws;
  const size_t SZ = 8192ull * 1024 * 2;
  const size_t WSZ = 1024ull * 1024 * 2;

  unsigned short* xb   = (unsigned short*)(ws);
  unsigned short* qb   = (unsigned short*)(ws + SZ);   // qb,kb,vtb contiguous
  unsigned short* kb   = (unsigned short*)(ws + 2 * SZ);
  unsigned short* vtb  = (unsigned short*)(ws + 3 * SZ);
  unsigned short* attn = (unsigned short*)(ws + 4 * SZ);
  unsigned short* hb   = (unsigned short*)(ws + 5 * SZ);
  unsigned short* r1   = qb;
  unsigned short* ffb  = kb;
  unsigned short* r2   = attn;

  char* wreg = ws + 6 * SZ;
  unsigned short* wqb = (unsigned short*)(wreg);
  unsigned short* w1b = (unsigned short*)(wreg + 4 * WSZ);
  unsigned short* w2b = (unsigned short*)(wreg + 6 * WSZ);
  unsigned short* wob = (unsigned short*)(wreg + 3 * WSZ);
  unsigned short* smal = (unsigned short*)(wreg + 8 * WSZ);
  unsigned short* bqb = smal;
  unsigned short* bkb = smal + 1024;
  unsigned short* bvb = smal + 2048;
  unsigned short* bob = smal + 3072;
  unsigned short* b1b = smal + 4096;
  unsigned short* b2b = smal + 6144;
  unsigned short* a1b = smal + 7168;
  unsigned short* g1b = smal + 9216;
  unsigned short* a2b = smal + 11264;
  unsigned short* g2b = smal + 13312;
  int* flag = (int*)(wreg + 8 * WSZ + 64 * 1024);

  CvtArgs ca;
  unsigned short* wkb = wqb + 1024 * 1024;
  unsigned short* wvb = wqb + 2 * 1024 * 1024;
  unsigned short* dsts[17] = {xb, wqb, bqb, wkb, bkb, wvb, bvb, wob, bob,
                              a1b, g1b, w1b, b1b, w2b, b2b, a2b, g2b};
  ca.cum4[0] = 0;
  for (int i = 0; i < 17; ++i) {
    ca.src[i] = d_in[i];
    ca.dst[i] = dsts[i];
    ca.cum4[i + 1] = ca.cum4[i] + in_sizes[i] / 4;
  }
  const int total4 = ca.cum4[17];

  // one-time: allow big dynamic LDS for the gemm2 instantiations
  static bool attr_set = false;
  if (!attr_set) {
    attr_set = true;
    hipFuncSetAttribute(reinterpret_cast<const void*>(gemm2<4, 128>),
                        hipFuncAttributeMaxDynamicSharedMemorySize, 147456);
    hipFuncSetAttribute(reinterpret_cast<const void*>(gemm2<3, 256>),
                        hipFuncAttributeMaxDynamicSharedMemorySize, 131072);
    hipFuncSetAttribute(reinterpret_cast<const void*>(gemm2<2, 128>),
                        hipFuncAttributeMaxDynamicSharedMemorySize, 147456);
  }

  dim3 blk(256);
  dim3 blk512(512);
  detect_dtype<<<1, blk, 0, stream>>>((const unsigned int*)d_in[0], flag);
  cvt_all<<<(total4 + 255) / 256, blk, 0, stream>>>(ca, flag, total4);

  gemm2<4, 128><<<dim3(12, 64), blk512, 147456, stream>>>(xb, wqb, bqb, nullptr, qb, 8192, 3072, 1024);
  attn_fwd<<<dim3(8, 64), blk, 0, stream>>>(qb, kb, vtb, attn);
  gemm2<2, 128><<<dim3(4, 64), blk512, 147456, stream>>>(attn, wob, bob, xb, r1, 8192, 1024, 1024);
  norm_affine<false><<<8192, blk, 0, stream>>>(r1, a1b, g1b, hb, nullptr);
  gemm2<3, 256><<<dim3(8, 32), blk512, 131072, stream>>>(hb, w1b, b1b, nullptr, ffb, 8192, 2048, 1024);
  gemm2<2, 128><<<dim3(4, 64), blk512, 147456, stream>>>(ffb, w2b, b2b, hb, r2, 8192, 1024, 2048);
  norm_affine<true><<<8192, blk, 0, stream>>>(r2, a2b, g2b, d_out, flag);
}

// Round 8
// 399.035 us; speedup vs baseline: 1.0729x; 1.0448x over previous
//
#include <hip/hip_runtime.h>

// ---------------------------------------------------------------------------
// TransformerBlock (B=4,S=2048,E=1024,H=16,Dh=64), fp32 (or bf16) in, fp32
// (or bf16) out — dtype auto-detected; all compute in bf16 MFMA w/ fp32 accum.
// Pipeline: cvt-to-bf16 -> fused QKV gemm -> flash attn -> Wo gemm (+x) ->
//           norm1 -> FFN1 (relu) -> FFN2 (+h) -> norm2 -> out
// R15:
//   - GEMMs: exact R4 config (best measured 404.4us): QKV gemm2<4,256>
//     (12,32); Wo/FFN2 gemm2<2,128> (4,64); FFN1 gemm2<3,256> (8,32).
//     R7's QKV<4,128>/768blk regressed ~12us (B-traffic > quantization win).
//   - attn: Q-tile 512 (8 waves, grid (4,64)).  Per-wave work & registers
//     unchanged (64 Q-rows/wave); one gl2lds covers a full 64x64 K/V tile
//     (2 loads/iter, vmcnt(2)); staging bytes halved, K/V re-reads 8x->4x.
//     P buffer 32KB -> LDS exactly 64KB.
// ---------------------------------------------------------------------------

typedef __attribute__((ext_vector_type(8))) short s16x8;
typedef __attribute__((ext_vector_type(4))) short s16x4;
typedef __attribute__((ext_vector_type(4))) unsigned short u16x4;
typedef __attribute__((ext_vector_type(4))) float f32x4;

__device__ __forceinline__ float bf2f(unsigned short u) {
  unsigned int v = ((unsigned int)u) << 16;
  return __builtin_bit_cast(float, v);
}
__device__ __forceinline__ unsigned short f2bf(float f) {
  unsigned int u = __builtin_bit_cast(unsigned int, f);
  u += 0x7fffu + ((u >> 16) & 1u);   // RNE
  return (unsigned short)(u >> 16);
}
// pack two f32 -> two bf16 (truncate) in one v_perm_b32
__device__ __forceinline__ unsigned int pkbf_trunc(float f0, float f1) {
  return __builtin_amdgcn_perm(__builtin_bit_cast(unsigned int, f1),
                               __builtin_bit_cast(unsigned int, f0), 0x07060302u);
}
__device__ __forceinline__ f32x4 mfma16(s16x8 a, s16x8 b, f32x4 c) {
  return __builtin_amdgcn_mfma_f32_16x16x32_bf16(a, b, c, 0, 0, 0);
}
__device__ __forceinline__ void gl2lds16(const unsigned short* g, unsigned short* l) {
  __builtin_amdgcn_global_load_lds(
      (const __attribute__((address_space(1))) unsigned int*)(g),
      (__attribute__((address_space(3))) unsigned int*)(l), 16, 0, 0);
}

// ---------------------------------------------------------------------------
__global__ void detect_dtype(const unsigned int* __restrict__ x, int* __restrict__ flag) {
  const int tid = threadIdx.x;
  int cnt = 0;
  for (int i = tid; i < 2048; i += 256) {
    const unsigned e = (x[i] >> 7) & 0xFF;
    cnt += (e >= 100 && e <= 150) ? 1 : 0;
  }
#pragma unroll
  for (int off = 32; off >= 1; off >>= 1) cnt += __shfl_xor(cnt, off);
  __shared__ int red[4];
  if ((tid & 63) == 0) red[tid >> 6] = cnt;
  __syncthreads();
  if (tid == 0) *flag = ((red[0] + red[1] + red[2] + red[3]) > 1536) ? 1 : 0;
}

// ---------------------------------------------------------------------------
struct CvtArgs {
  const void* src[17];
  unsigned short* dst[17];
  int cum4[18];
};

__global__ __launch_bounds__(256) void cvt_all(CvtArgs a, const int* __restrict__ flag, int total4) {
  const int i = blockIdx.x * 256 + threadIdx.x;
  if (i >= total4) return;
  int lo = 0, hi = 17;
  while (hi - lo > 1) {
    const int mid = (lo + hi) >> 1;
    if (i >= a.cum4[mid]) lo = mid; else hi = mid;
  }
  const int off4 = i - a.cum4[lo];
  if (*flag) {
    const u16x4* s = (const u16x4*)a.src[lo];
    *(u16x4*)&a.dst[lo][off4 * 4] = s[off4];
  } else {
    const float4* s = (const float4*)a.src[lo];
    const float4 v = s[off4];
    u16x4 o;
    o[0] = f2bf(v.x); o[1] = f2bf(v.y); o[2] = f2bf(v.z); o[3] = f2bf(v.w);
    *(u16x4*)&a.dst[lo][off4 * 4] = o;
  }
}

// ---------------------------------------------------------------------------
// GEMM: C = A(MxK) * W(NxK)^T + bias.  BN=256, BK=64, 512 threads,
// 8 waves 2Mx4N (per-wave (BM/2)x64).
// EPI 2: += resid. EPI 3: relu. EPI 4: fused QKV split (Q scaled, V^T scatter).
// ---------------------------------------------------------------------------
#define QOFF 8388608L
#define SCALE2 0.18033688011f  // (1/8) * log2(e)

template <int EPI, int BM>
__global__ __launch_bounds__(512, 1) void gemm2(
    const unsigned short* __restrict__ A, const unsigned short* __restrict__ W,
    const unsigned short* __restrict__ bias, const unsigned short* __restrict__ resid,
    unsigned short* __restrict__ out, int M, int N, int K) {
  constexpr int NBUF = (BM == 256) ? 2 : 3;
  constexpr int BUFE = (BM + 256) * 64;   // shorts per buffer
  extern __shared__ unsigned short sh[];

  const int tid = threadIdx.x;
  const int lane = tid & 63;
  const int wave = tid >> 6;
  const int qd = lane >> 4;
  const int c = lane & 15;
  const int wr = (wave >> 2) * (BM / 2);
  const int wc = (wave & 3) * 64;

  // XCD-bijective block swizzle (nwg % 8 == 0 for all our grids).
  const int nx = gridDim.x, ny = gridDim.y;
  const int nwg = nx * ny;
  int lin = blockIdx.y * nx + blockIdx.x;
  lin = (lin & 7) * (nwg >> 3) + (lin >> 3);
  const int by = lin % ny;            // M varies fastest within an XCD chunk
  const int bx = lin / ny;            // -> B-panel resident per XCD-L2
  const long m0 = (long)by * BM;
  const long n0 = (long)bx * 256;

  // staging: thread owns row (tid>>3) of a 64-row quarter, chunk tid&7,
  // source col XOR-swizzled so LDS dest stays linear; reads unswizzle.
  const int srow = tid >> 3;
  const int scc = ((tid & 7) ^ (srow & 7)) * 8;
  const unsigned short* Asrc = A + (m0 + srow) * (long)K + scc;
  const unsigned short* Wsrc = W + (n0 + srow) * (long)K + scc;
  const int lofs = tid * 8;

  f32x4 acc[BM / 32][4] = {};

  const int NT = K >> 6;

  auto stA = [&](int sel, int tt, int q) {
    gl2lds16(Asrc + (long)q * 64 * K + (long)tt * 64, sh + sel * BUFE + q * 4096 + lofs);
  };
  auto stB = [&](int sel, int tt, int q) {
    gl2lds16(Wsrc + (long)q * 64 * K + (long)tt * 64,
             sh + sel * BUFE + BM * 64 + q * 4096 + lofs);
  };

  // prologue (issue order = age order for the counted waits)
  if constexpr (BM == 256) {
    stB(0, 0, 0); stB(0, 0, 1); stB(0, 0, 2); stB(0, 0, 3);
    stA(0, 0, 0); stA(0, 0, 2); stA(0, 0, 1); stA(0, 0, 3);
  } else {
    stB(0, 0, 0); stB(0, 0, 1); stB(0, 0, 2); stB(0, 0, 3); stA(0, 0, 0); stA(0, 0, 1);
    stB(1, 1, 0); stB(1, 1, 1); stB(1, 1, 2); stB(1, 1, 3); stA(1, 1, 0); stA(1, 1, 1);
  }

  int cur = 0;
  for (int t = 0; t < NT; ++t) {
    const unsigned short* Ab = sh + cur * BUFE;
    const unsigned short* Bb = Ab + BM * 64;

    if constexpr (BM == 256) {
      const bool dost = (t + 1 < NT);
      const int ns = cur ^ 1;
      // B,A-q0,A-q2 of tile t landed; its A-q1,A-q3 (newest 2) still in flight
      asm volatile("s_waitcnt vmcnt(2)\n\ts_barrier" ::: "memory");
      s16x8 bfr[4][2], af[4][2];
#pragma unroll
      for (int nt = 0; nt < 4; ++nt)
#pragma unroll
        for (int ks = 0; ks < 2; ++ks)
          bfr[nt][ks] = *(const s16x8*)&Bb[(wc + nt * 16 + c) * 64 +
                                           (((ks * 4 + qd) ^ (c & 7)) * 8)];
#pragma unroll
      for (int mt = 0; mt < 4; ++mt)
#pragma unroll
        for (int ks = 0; ks < 2; ++ks)
          af[mt][ks] = *(const s16x8*)&Ab[(wr + mt * 16 + c) * 64 +
                                          (((ks * 4 + qd) ^ (c & 7)) * 8)];
      if (dost) { stB(ns, t + 1, 0); stB(ns, t + 1, 1); stB(ns, t + 1, 2); stB(ns, t + 1, 3); }
      __builtin_amdgcn_s_setprio(1);
#pragma unroll
      for (int mt = 0; mt < 4; ++mt)
#pragma unroll
        for (int nt = 0; nt < 4; ++nt)
#pragma unroll
          for (int ks = 0; ks < 2; ++ks)
            acc[mt][nt] = mfma16(af[mt][ks], bfr[nt][ks], acc[mt][nt]);
      __builtin_amdgcn_s_setprio(0);
      // drain tile t's A-q1/A-q3 (leave t+1's 4 B loads in flight)
      if (dost) asm volatile("s_waitcnt vmcnt(4)\n\ts_barrier" ::: "memory");
      else      asm volatile("s_waitcnt vmcnt(0)\n\ts_barrier" ::: "memory");
#pragma unroll
      for (int mt = 0; mt < 4; ++mt)
#pragma unroll
        for (int ks = 0; ks < 2; ++ks)
          af[mt][ks] = *(const s16x8*)&Ab[(wr + 64 + mt * 16 + c) * 64 +
                                          (((ks * 4 + qd) ^ (c & 7)) * 8)];
      if (dost) { stA(ns, t + 1, 0); stA(ns, t + 1, 2); stA(ns, t + 1, 1); stA(ns, t + 1, 3); }
      __builtin_amdgcn_s_setprio(1);
#pragma unroll
      for (int mt = 0; mt < 4; ++mt)
#pragma unroll
        for (int nt = 0; nt < 4; ++nt)
#pragma unroll
          for (int ks = 0; ks < 2; ++ks)
            acc[4 + mt][nt] = mfma16(af[mt][ks], bfr[nt][ks], acc[4 + mt][nt]);
      __builtin_amdgcn_s_setprio(0);
    } else {
      // tile t landed; tile t+1's 6 loads stay in flight
      if (t + 1 < NT) asm volatile("s_waitcnt vmcnt(6)\n\ts_barrier" ::: "memory");
      else            asm volatile("s_waitcnt vmcnt(0)\n\ts_barrier" ::: "memory");
      s16x8 bfr[4][2], af[4][2];
#pragma unroll
      for (int nt = 0; nt < 4; ++nt)
#pragma unroll
        for (int ks = 0; ks < 2; ++ks)
          bfr[nt][ks] = *(const s16x8*)&Bb[(wc + nt * 16 + c) * 64 +
                                           (((ks * 4 + qd) ^ (c & 7)) * 8)];
#pragma unroll
      for (int mt = 0; mt < 4; ++mt)
#pragma unroll
        for (int ks = 0; ks < 2; ++ks)
          af[mt][ks] = *(const s16x8*)&Ab[(wr + mt * 16 + c) * 64 +
                                          (((ks * 4 + qd) ^ (c & 7)) * 8)];
      if (t + 2 < NT) {
        const int ns = (cur >= 1) ? cur - 1 : 2;   // (cur+2)%3
        stB(ns, t + 2, 0); stB(ns, t + 2, 1); stB(ns, t + 2, 2); stB(ns, t + 2, 3);
        stA(ns, t + 2, 0); stA(ns, t + 2, 1);
      }
      __builtin_amdgcn_s_setprio(1);
#pragma unroll
      for (int mt = 0; mt < 4; ++mt)
#pragma unroll
        for (int nt = 0; nt < 4; ++nt)
#pragma unroll
          for (int ks = 0; ks < 2; ++ks)
            acc[mt][nt] = mfma16(af[mt][ks], bfr[nt][ks], acc[mt][nt]);
      __builtin_amdgcn_s_setprio(0);
    }
    cur = (cur + 1 == NBUF) ? 0 : cur + 1;
  }

#pragma unroll
  for (int nt = 0; nt < 4; ++nt) {
    const int gn = (int)n0 + wc + nt * 16 + c;
    const float bv = bf2f(bias[gn]);
#pragma unroll
    for (int mt = 0; mt < BM / 32; ++mt) {
      const long gmb = m0 + wr + mt * 16 + qd * 4;
      if constexpr (EPI == 2) {
#pragma unroll
        for (int r = 0; r < 4; ++r) {
          const long gm = gmb + r;
          const float v = acc[mt][nt][r] + bv + bf2f(resid[gm * N + gn]);
          out[gm * N + gn] = f2bf(v);
        }
      } else if constexpr (EPI == 3) {
#pragma unroll
        for (int r = 0; r < 4; ++r) {
          const long gm = gmb + r;
          float v = acc[mt][nt][r] + bv;
          v = fmaxf(v, 0.0f);
          out[gm * N + gn] = f2bf(v);
        }
      } else {  // EPI == 4: fused QKV
        const int seg = gn >> 10;       // 0=Q, 1=K, 2=V  (uniform per block)
        const int nn = gn & 1023;
        if (seg == 0) {                 // Q plain (s,1024), pre-scaled
#pragma unroll
          for (int r = 0; r < 4; ++r)
            out[(gmb + r) * 1024 + nn] = f2bf((acc[mt][nt][r] + bv) * SCALE2);
        } else if (seg == 1) {          // K plain (s,1024)
#pragma unroll
          for (int r = 0; r < 4; ++r)
            (out + QOFF)[(gmb + r) * 1024 + nn] = f2bf(acc[mt][nt][r] + bv);
        } else {                        // V^T (b,h,d,s)
          const int h = nn >> 6, d = nn & 63;
          const long b = gmb >> 11;
          const int s = (int)(gmb & 2047);
          s16x4 pv;
#pragma unroll
          for (int r = 0; r < 4; ++r) pv[r] = (short)f2bf(acc[mt][nt][r] + bv);
          *(s16x4*)&(out + 2 * QOFF)[((b * 16 + h) * 64L + d) * 2048 + s] = pv;
        }
      }
    }
  }
}

// ---------------------------------------------------------------------------
// Flash attention, R15: Q-tile 512, 8 waves (512 thr), grid (4,64).
// KV tile = 64 rows, double-buffered; one gl2lds covers a full 64x64 tile
// (2 loads/iter, s_waitcnt vmcnt(2)).  Per-wave layout identical to R4
// (64 Q-rows/wave: 2 halves x 32).  LDS 64 KB (K 2x8 + V 2x8 + P 32).
// ---------------------------------------------------------------------------
#define ATT_S 2048

__global__ __launch_bounds__(512)
__attribute__((amdgpu_waves_per_eu(2, 2))) void attn_fwd(
    const unsigned short* __restrict__ Q, const unsigned short* __restrict__ K,
    const unsigned short* __restrict__ VT, unsigned short* __restrict__ O) {
  __shared__ unsigned short SH[32768];  // 64 KB
  unsigned short* Kb0 = SH;             // [t][d] 64x64 swizzled (8 KB)
  unsigned short* Kb1 = SH + 4096;
  unsigned short* Vb0 = SH + 8192;      // [d][t] 64x64 swizzled
  unsigned short* Vb1 = SH + 12288;
  unsigned short* Pl  = SH + 16384;     // [m][t] 256x64 swizzled (32 KB)

  const int bh = blockIdx.y;
  const int q0 = blockIdx.x * 512;
  const long b = bh >> 4;
  const int h = bh & 15;
  const unsigned short* Qg = Q + (b * 2048) * 1024 + h * 64;
  const unsigned short* Kg = K + (b * 2048) * 1024 + h * 64;
  const unsigned short* Vg = VT + (long)bh * 64 * 2048;

  const int tid = threadIdx.x;
  const int wave = tid >> 6, lane = tid & 63;
  const int qd = lane >> 4, c = lane & 15;
  const int mb = wave * 32;             // row base within a 256-row half

  // staging: 512 threads cover a full 64x64 tile: row tid>>3, chunk tid&7
  const int srow = tid >> 3;
  const int sccs = ((tid & 7) ^ (srow & 7)) * 8;

  s16x8 qf[2][2][2];  // [half][mt][ks]
#pragma unroll
  for (int h2 = 0; h2 < 2; ++h2)
#pragma unroll
    for (int mt = 0; mt < 2; ++mt)
#pragma unroll
      for (int ks = 0; ks < 2; ++ks)
        qf[h2][mt][ks] = *(const s16x8*)&Qg[(long)(q0 + h2 * 256 + mb + mt * 16 + c) * 1024 +
                                            ks * 32 + qd * 8];

  s16x8 ones;
#pragma unroll
  for (int i = 0; i < 8; ++i) ones[i] = (short)0x3F80;

  f32x4 oacc[2][4][2] = {};  // [half][dt][mt]
  f32x4 lacc[2][2] = {};     // [half][mt]

  // preload tile 0 (one gl2lds per K/V tile)
  gl2lds16(Kg + (long)srow * 1024 + sccs, &Kb0[tid * 8]);
  gl2lds16(Vg + (long)srow * 2048 + sccs, &Vb0[tid * 8]);

  for (int it = 0; it < 32; ++it) {
    const int p = it & 1;
    unsigned short* Kc = p ? Kb1 : Kb0;
    unsigned short* Vc = p ? Vb1 : Vb0;
    unsigned short* Kn = p ? Kb0 : Kb1;
    unsigned short* Vn = p ? Vb0 : Vb1;
    const int kvn = (it < 31) ? (it + 1) * 64 : 31 * 64;  // clamp keeps vmcnt math uniform
    gl2lds16(Kg + (long)(kvn + srow) * 1024 + sccs, &Kn[tid * 8]);
    gl2lds16(Vg + (long)srow * 2048 + kvn + sccs, &Vn[tid * 8]);

    // tile `it` fully landed; tile it+1's 2 loads stay in flight
    asm volatile("s_waitcnt vmcnt(2)\n\ts_barrier" ::: "memory");

#pragma unroll
    for (int h2 = 0; h2 < 2; ++h2) {
      f32x4 sacc[4][2] = {};
#pragma unroll
      for (int ks = 0; ks < 2; ++ks) {
        const int ch = ((ks * 4 + qd) ^ (c & 7)) * 8;
        s16x8 kf[4];
#pragma unroll
        for (int tt = 0; tt < 4; ++tt)
          kf[tt] = *(const s16x8*)&Kc[(tt * 16 + c) * 64 + ch];
#pragma unroll
        for (int mt = 0; mt < 2; ++mt)
#pragma unroll
          for (int tt = 0; tt < 4; ++tt)
            sacc[tt][mt] = mfma16(kf[tt], qf[h2][mt][ks], sacc[tt][mt]);
      }

      // exp2 + pack into wave-private P rows (8-chunk XOR swizzle, row len 64)
#pragma unroll
      for (int mt = 0; mt < 2; ++mt) {
        const int ml = mb + mt * 16 + c;
#pragma unroll
        for (int tt = 0; tt < 4; ++tt) {
          unsigned int pk[2];
          pk[0] = pkbf_trunc(__builtin_amdgcn_exp2f(sacc[tt][mt][0]),
                             __builtin_amdgcn_exp2f(sacc[tt][mt][1]));
          pk[1] = pkbf_trunc(__builtin_amdgcn_exp2f(sacc[tt][mt][2]),
                             __builtin_amdgcn_exp2f(sacc[tt][mt][3]));
          const int chw = ((tt * 2 + (qd >> 1)) ^ (ml & 7)) * 8 + (qd & 1) * 4;
          *(uint2*)&Pl[ml * 64 + chw] = *(uint2*)pk;
        }
      }
      asm volatile("s_waitcnt lgkmcnt(0)" ::: "memory");  // own-wave P visible

#pragma unroll
      for (int ks = 0; ks < 2; ++ks) {
        const int vch = ((ks * 4 + qd) ^ (c & 7)) * 8;
        s16x8 vf[4], pf[2];
#pragma unroll
        for (int dt = 0; dt < 4; ++dt)
          vf[dt] = *(const s16x8*)&Vc[(dt * 16 + c) * 64 + vch];
#pragma unroll
        for (int mt = 0; mt < 2; ++mt) {
          const int pr = mb + mt * 16 + c;
          pf[mt] = *(const s16x8*)&Pl[pr * 64 + (((ks * 4 + qd) ^ (pr & 7)) * 8)];
        }
#pragma unroll
        for (int mt = 0; mt < 2; ++mt) {
#pragma unroll
          for (int dt = 0; dt < 4; ++dt)
            oacc[h2][dt][mt] = mfma16(vf[dt], pf[mt], oacc[h2][dt][mt]);
          lacc[h2][mt] = mfma16(ones, pf[mt], lacc[h2][mt]);
        }
      }
    }

    // all waves done reading this buffer before next iter's prefetch hits it
    asm volatile("s_barrier" ::: "memory");
  }

#pragma unroll
  for (int h2 = 0; h2 < 2; ++h2)
#pragma unroll
    for (int mt = 0; mt < 2; ++mt) {
      const float inv = 1.0f / lacc[h2][mt][0];
      const int s = q0 + h2 * 256 + mb + mt * 16 + c;
      const long ob = (b * (long)ATT_S + s) * 1024L + h * 64;
#pragma unroll
      for (int dt = 0; dt < 4; ++dt) {
        s16x4 ov;
#pragma unroll
        for (int r = 0; r < 4; ++r) ov[r] = (short)f2bf(oacc[h2][dt][mt][r] * inv);
        *(s16x4*)&O[ob + dt * 16 + qd * 4] = ov;
      }
    }
}

// ---------------------------------------------------------------------------
template <bool FINAL>
__global__ __launch_bounds__(256) void norm_affine(
    const unsigned short* __restrict__ X, const unsigned short* __restrict__ av,
    const unsigned short* __restrict__ bv, void* __restrict__ outv,
    const int* __restrict__ flag) {
  const int row = blockIdx.x;
  const int s = row & 2047;
  const unsigned short* xr = X + (long)row * 1024;
  const int tid = threadIdx.x;
  const u16x4 u = *(const u16x4*)&xr[tid * 4];
  float v[4];
  float s1 = 0.f, s2 = 0.f;
#pragma unroll
  for (int i = 0; i < 4; ++i) {
    v[i] = bf2f(u[i]);
    s1 += v[i];
    s2 += v[i] * v[i];
  }
#pragma unroll
  for (int off = 32; off >= 1; off >>= 1) {
    s1 += __shfl_xor(s1, off);
    s2 += __shfl_xor(s2, off);
  }
  __shared__ float red[8];
  const int wave = tid >> 6, lane = tid & 63;
  if (lane == 0) {
    red[wave * 2] = s1;
    red[wave * 2 + 1] = s2;
  }
  __syncthreads();
  s1 = red[0] + red[2] + red[4] + red[6];
  s2 = red[1] + red[3] + red[5] + red[7];
  const float mean = s1 * (1.0f / 1024.0f);
  const float var = fmaxf(s2 * (1.0f / 1024.0f) - mean * mean, 0.0f);
  const float rstd = rsqrtf(var + 1e-5f);
  const float aa = bf2f(av[s]), bb = bf2f(bv[s]);
  float o[4];
#pragma unroll
  for (int i = 0; i < 4; ++i) o[i] = aa * (v[i] - mean) * rstd + bb;
  bool as_bf16 = true;
  if constexpr (FINAL) as_bf16 = (*flag != 0);
  if (as_bf16) {
    u16x4 ob;
#pragma unroll
    for (int i = 0; i < 4; ++i) ob[i] = f2bf(o[i]);
    *(u16x4*)&((unsigned short*)outv)[(long)row * 1024 + tid * 4] = ob;
  } else {
    float4 of = {o[0], o[1], o[2], o[3]};
    *(float4*)&((float*)outv)[(long)row * 1024 + tid * 4] = of;
  }
}

// ---------------------------------------------------------------------------
extern "C" void kernel_launch(void* const* d_in, const int* in_sizes, int n_in,
                              void* d_out, int out_size, void* d_ws, size_t ws_size,
                              hipStream_t stream) {
  char* ws = (char*)d_ws;
  const size_t SZ = 8192ull * 1024 * 2;
  const size_t WSZ = 1024ull * 1024 * 2;

  unsigned short* xb   = (unsigned short*)(ws);
  unsigned short* qb   = (unsigned short*)(ws + SZ);   // qb,kb,vtb contiguous
  unsigned short* kb   = (unsigned short*)(ws + 2 * SZ);
  unsigned short* vtb  = (unsigned short*)(ws + 3 * SZ);
  unsigned short* attn = (unsigned short*)(ws + 4 * SZ);
  unsigned short* hb   = (unsigned short*)(ws + 5 * SZ);
  unsigned short* r1   = qb;
  unsigned short* ffb  = kb;
  unsigned short* r2   = attn;

  char* wreg = ws + 6 * SZ;
  unsigned short* wqb = (unsigned short*)(wreg);
  unsigned short* w1b = (unsigned short*)(wreg + 4 * WSZ);
  unsigned short* w2b = (unsigned short*)(wreg + 6 * WSZ);
  unsigned short* wob = (unsigned short*)(wreg + 3 * WSZ);
  unsigned short* smal = (unsigned short*)(wreg + 8 * WSZ);
  unsigned short* bqb = smal;
  unsigned short* bkb = smal + 1024;
  unsigned short* bvb = smal + 2048;
  unsigned short* bob = smal + 3072;
  unsigned short* b1b = smal + 4096;
  unsigned short* b2b = smal + 6144;
  unsigned short* a1b = smal + 7168;
  unsigned short* g1b = smal + 9216;
  unsigned short* a2b = smal + 11264;
  unsigned short* g2b = smal + 13312;
  int* flag = (int*)(wreg + 8 * WSZ + 64 * 1024);

  CvtArgs ca;
  unsigned short* wkb = wqb + 1024 * 1024;
  unsigned short* wvb = wqb + 2 * 1024 * 1024;
  unsigned short* dsts[17] = {xb, wqb, bqb, wkb, bkb, wvb, bvb, wob, bob,
                              a1b, g1b, w1b, b1b, w2b, b2b, a2b, g2b};
  ca.cum4[0] = 0;
  for (int i = 0; i < 17; ++i) {
    ca.src[i] = d_in[i];
    ca.dst[i] = dsts[i];
    ca.cum4[i + 1] = ca.cum4[i] + in_sizes[i] / 4;
  }
  const int total4 = ca.cum4[17];

  // one-time: allow big dynamic LDS for the gemm2 instantiations
  static bool attr_set = false;
  if (!attr_set) {
    attr_set = true;
    hipFuncSetAttribute(reinterpret_cast<const void*>(gemm2<4, 256>),
                        hipFuncAttributeMaxDynamicSharedMemorySize, 131072);
    hipFuncSetAttribute(reinterpret_cast<const void*>(gemm2<3, 256>),
                        hipFuncAttributeMaxDynamicSharedMemorySize, 131072);
    hipFuncSetAttribute(reinterpret_cast<const void*>(gemm2<2, 128>),
                        hipFuncAttributeMaxDynamicSharedMemorySize, 147456);
  }

  dim3 blk(256);
  dim3 blk512(512);
  detect_dtype<<<1, blk, 0, stream>>>((const unsigned int*)d_in[0], flag);
  cvt_all<<<(total4 + 255) / 256, blk, 0, stream>>>(ca, flag, total4);

  gemm2<4, 256><<<dim3(12, 32), blk512, 131072, stream>>>(xb, wqb, bqb, nullptr, qb, 8192, 3072, 1024);
  attn_fwd<<<dim3(4, 64), blk512, 0, stream>>>(qb, kb, vtb, attn);
  gemm2<2, 128><<<dim3(4, 64), blk512, 147456, stream>>>(attn, wob, bob, xb, r1, 8192, 1024, 1024);
  norm_affine<false><<<8192, blk, 0, stream>>>(r1, a1b, g1b, hb, nullptr);
  gemm2<3, 256><<<dim3(8, 32), blk512, 131072, stream>>>(hb, w1b, b1b, nullptr, ffb, 8192, 2048, 1024);
  gemm2<2, 128><<<dim3(4, 64), blk512, 147456, stream>>>(ffb, w2b, b2b, hb, r2, 8192, 1024, 2048);
  norm_affine<true><<<8192, blk, 0, stream>>>(r2, a2b, g2b, d_out, flag);
}